// Round 4
// baseline (37491.815 us; speedup 1.0000x reference)
//
#include <hip/hip_runtime.h>
#include <stdint.h>

#define NEG_INF -100000000.0f

typedef unsigned short u16;
typedef unsigned long long u64;
typedef __attribute__((ext_vector_type(8))) short v8s;
typedef __attribute__((ext_vector_type(4))) short v4s;
typedef __attribute__((ext_vector_type(4))) float v4f;

__device__ __forceinline__ float bf2f(u16 h){ return __uint_as_float(((unsigned)h)<<16); }
__device__ __forceinline__ u16 f2bf(float f){
  unsigned u = __float_as_uint(f);
  u = u + 0x7fffu + ((u>>16)&1u);
  return (u16)(u>>16);
}
__device__ __forceinline__ float sigm(float x){ return 1.0f/(1.0f+__expf(-x)); }
__device__ __forceinline__ float ftanh(float x){
  x = fminf(15.0f, fmaxf(-15.0f, x));
  float e = __expf(2.0f*x);
  return (e-1.0f)/(e+1.0f);
}

// coherent (write-through / L2-bypass) 16B h-fragment access, 2x u64 relaxed agent atomics
__device__ __forceinline__ v8s load_h16(const u16* p){
  union { u64 q[2]; v8s v; } u;
  u.q[0] = __hip_atomic_load((const u64*)p,     __ATOMIC_RELAXED, __HIP_MEMORY_SCOPE_AGENT);
  u.q[1] = __hip_atomic_load((const u64*)(p+4), __ATOMIC_RELAXED, __HIP_MEMORY_SCOPE_AGENT);
  return u.v;
}
__device__ __forceinline__ void store_h16(u16* p, u64 a, u64 b){
  __hip_atomic_store((u64*)p,     a, __ATOMIC_RELAXED, __HIP_MEMORY_SCOPE_AGENT);
  __hip_atomic_store((u64*)(p+4), b, __ATOMIC_RELAXED, __HIP_MEMORY_SCOPE_AGENT);
}

// ---------------------------------------------------------------------------
// Fused f32 -> bf16 arena conversion (all 31 float params in one launch)
// ---------------------------------------------------------------------------
struct CvtTab {
  const float* src[31];
  unsigned off[31];
  unsigned n[31];
  unsigned total;
};

__global__ __launch_bounds__(256) void cvt_all(CvtTab tab, u16* __restrict__ arena){
  unsigned e0 = (blockIdx.x*256u + threadIdx.x)*8u;
  if (e0 >= tab.total) return;
  int s = 0;
#pragma unroll 1
  for (int i = 1; i < 31; ++i) if (e0 >= tab.off[i]) s = i;
  unsigned rel = e0 - tab.off[s];
  const float* sp = tab.src[s] + rel;
  unsigned nn = tab.n[s];
  union { u16 h[8]; v8s v; } o;
  if (rel + 8 <= nn) {
    float4 a = *(const float4*)sp;
    float4 b = *(const float4*)(sp+4);
    o.h[0]=f2bf(a.x); o.h[1]=f2bf(a.y); o.h[2]=f2bf(a.z); o.h[3]=f2bf(a.w);
    o.h[4]=f2bf(b.x); o.h[5]=f2bf(b.y); o.h[6]=f2bf(b.z); o.h[7]=f2bf(b.w);
  } else {
#pragma unroll
    for (int k = 0; k < 8; ++k) o.h[k] = (rel + k < nn) ? f2bf(sp[k]) : (u16)0;
  }
  *(v8s*)(arena + e0) = o.v;
}

// ---------------------------------------------------------------------------
// Generic bf16 GEMM: C[M][N] = A[M][K] @ B[N][K]^T (+bias1+bias2)(+tanh)(+C)
// ---------------------------------------------------------------------------
#define GF_OUTBF16 1
#define GF_TANH    2
#define GF_ACCUM   4

__global__ __launch_bounds__(256) void gemm_bf16(
    const u16* __restrict__ A, long long lda,
    const u16* __restrict__ B,
    const u16* __restrict__ bias1, const u16* __restrict__ bias2,
    void* __restrict__ Cout, long long ldc,
    int M, int Nn, int K, int flags)
{
  __shared__ u16 As[8192];
  __shared__ u16 Bs[8192];
  int tid = threadIdx.x;
  int lane = tid & 63, w = tid >> 6;
  int wm = w >> 1, wn = w & 1;
  int bm = blockIdx.x * 128, bn = blockIdx.y * 128;

  v4f acc[4][4];
#pragma unroll
  for (int i=0;i<4;++i)
#pragma unroll
    for (int j=0;j<4;++j) acc[i][j] = (v4f){0.f,0.f,0.f,0.f};

#pragma unroll 1
  for (int ko = 0; ko < K; ko += 64) {
    __syncthreads();
#pragma unroll
    for (int it = 0; it < 8; ++it) {
      int c = tid + 256*it;
      int half = c >> 10;
      int cc = c & 1023;
      int r = cc >> 3;
      int kcb = cc & 7;
      const u16* src;
      if (half == 0) {
        int row = min(bm + r, M-1);
        src = A + (size_t)row*(size_t)lda + ko + (kcb<<3);
      } else {
        int row = min(bn + r, Nn-1);
        src = B + (size_t)row*(size_t)K + ko + (kcb<<3);
      }
      v8s v = *(const v8s*)src;
      char* base = (char*)(half ? Bs : As);
      *(v8s*)(base + (r<<7) + ((kcb<<4) ^ ((r&7)<<4))) = v;
    }
    __syncthreads();
#pragma unroll
    for (int ks = 0; ks < 2; ++ks) {
      v8s af[4], bfr[4];
#pragma unroll
      for (int mt=0; mt<4; ++mt) {
        int r = wm*64 + mt*16 + (lane & 15);
        int kb = (ks<<6) + ((lane>>4)<<4);
        af[mt] = *(const v8s*)((const char*)As + (r<<7) + (kb ^ ((r&7)<<4)));
      }
#pragma unroll
      for (int nt=0; nt<4; ++nt) {
        int r = wn*64 + nt*16 + (lane & 15);
        int kb = (ks<<6) + ((lane>>4)<<4);
        bfr[nt] = *(const v8s*)((const char*)Bs + (r<<7) + (kb ^ ((r&7)<<4)));
      }
#pragma unroll
      for (int mt=0; mt<4; ++mt)
#pragma unroll
        for (int nt=0; nt<4; ++nt)
          acc[mt][nt] = __builtin_amdgcn_mfma_f32_16x16x32_bf16(af[mt], bfr[nt], acc[mt][nt], 0,0,0);
    }
  }

#pragma unroll
  for (int mt=0; mt<4; ++mt) {
#pragma unroll
    for (int nt=0; nt<4; ++nt) {
      int col = bn + wn*64 + nt*16 + (lane&15);
      if (col >= Nn) continue;
      float b = 0.f;
      if (bias1) b += bf2f(bias1[col]);
      if (bias2) b += bf2f(bias2[col]);
#pragma unroll
      for (int r=0; r<4; ++r) {
        int row = bm + wm*64 + mt*16 + ((lane>>4)<<2) + r;
        if (row >= M) continue;
        float v = acc[mt][nt][r] + b;
        if (flags & GF_ACCUM) v += ((float*)Cout)[(size_t)row*(size_t)ldc + col];
        if (flags & GF_TANH) v = ftanh(v);
        if (flags & GF_OUTBF16) ((u16*)Cout)[(size_t)row*(size_t)ldc + col] = f2bf(v);
        else                    ((float*)Cout)[(size_t)row*(size_t)ldc + col] = v;
      }
    }
  }
}

// ---------------------------------------------------------------------------
// Persistent bidirectional LSTM scan, fence-free cross-block sync.
// 32 blocks: dir = blk>>4, ug = blk&15 (32 units each). 4 waves = 4 gates.
// Whh slice held in REGISTERS for all 512 steps (128 VGPR/thread).
// h exchange: sc0sc1 write-through stores + relaxed agent atomic loads.
// Barrier: vmcnt-drained stores -> relaxed fetch_add; relaxed poll AFTER the
// x-projection of the next step (latency hidden); __syncthreads orders block.
// No __threadfence anywhere -> L2 stays warm for Wih/x streams.
// ---------------------------------------------------------------------------
template<int LAYER>
__global__ __launch_bounds__(256, 1) void lstm_scan(
    const u16* __restrict__ xsrc,      // L0: embW ; L1: h0
    const int* __restrict__ Xidx,      // L0 only
    const u16* __restrict__ Wih_f, const u16* __restrict__ Wih_b,
    const u16* __restrict__ Whh_f, const u16* __restrict__ Whh_b,
    const u16* __restrict__ bih_f, const u16* __restrict__ bhh_f,
    const u16* __restrict__ bih_b, const u16* __restrict__ bhh_b,
    u16* __restrict__ hbuf,            // [64][512][1024], this layer's output
    unsigned* __restrict__ bar)        // per-dir counters, 256B apart
{
  constexpr int NCX = (LAYER==0) ? 4 : 32;   // x-projection K/32 chunks
  constexpr int KX  = NCX*32;
  __shared__ float glds[8192];               // 4 gates x 64 n x 32 u
  __shared__ u16   hlds[2048];               // 64 n x 32 u

  const int tid = threadIdx.x, lane = tid & 63, w = tid >> 6;
  const int dir = blockIdx.x >> 4, ug = blockIdx.x & 15;
  const u16* Wih = dir ? Wih_b : Wih_f;
  const u16* Whh = dir ? Whh_b : Whh_f;
  unsigned* cnt = bar + dir*64;

  const int an = lane & 15;
  const int ak = (lane >> 4) << 3;

  const u16* wihp[2];
  v8s whh_reg[2][16];                        // Whh slice, register-resident
#pragma unroll
  for (int nt = 0; nt < 2; ++nt) {
    int j = w*512 + ug*32 + nt*16 + an;
    wihp[nt] = Wih + (size_t)j*KX;
    const u16* wp = Whh + (size_t)j*512;
#pragma unroll
    for (int kc = 0; kc < 16; ++kc)
      whh_reg[nt][kc] = *(const v8s*)(wp + kc*32 + ak);
  }

  const int u_pw = tid & 31, uj_pw = ug*32 + u_pw;
  float bsum[4];
  {
    const u16* bi = dir ? bih_b : bih_f;
    const u16* bh = dir ? bhh_b : bhh_f;
#pragma unroll
    for (int q = 0; q < 4; ++q)
      bsum[q] = bf2f(bi[q*512 + uj_pw]) + bf2f(bh[q*512 + uj_pw]);
  }
  float creg[8];
#pragma unroll
  for (int i = 0; i < 8; ++i) creg[i] = 0.f;

  for (int step = 0; step < 512; ++step) {
    const int t     = dir ? (511 - step) : step;
    const int tprev = dir ? (t + 1) : (t - 1);

    v4f acc[4][2];
#pragma unroll
    for (int i=0;i<4;++i){ acc[i][0]=(v4f){0,0,0,0}; acc[i][1]=(v4f){0,0,0,0}; }

    // ---- x-projection (independent of h_prev; overlaps barrier wait) ----
    {
      const u16* arow[4];
#pragma unroll
      for (int mt = 0; mt < 4; ++mt) {
        if constexpr (LAYER == 0) {
          int xr = Xidx[(mt*16 + an)*512 + t];
          arow[mt] = xsrc + (size_t)xr * 128;
        } else {
          arow[mt] = xsrc + ((size_t)((mt*16 + an)*512 + t) << 10);
        }
      }
#pragma unroll 4
      for (int kc = 0; kc < NCX; ++kc) {
        v8s af[4];
#pragma unroll
        for (int mt = 0; mt < 4; ++mt) af[mt] = *(const v8s*)(arow[mt] + kc*32 + ak);
#pragma unroll
        for (int nt = 0; nt < 2; ++nt) {
          v8s bfr = *(const v8s*)(wihp[nt] + kc*32 + ak);
#pragma unroll
          for (int mt = 0; mt < 4; ++mt)
            acc[mt][nt] = __builtin_amdgcn_mfma_f32_16x16x32_bf16(af[mt], bfr, acc[mt][nt], 0,0,0);
        }
      }
    }

    // ---- wait for previous step's h (relaxed poll, no cache maintenance) ----
    if (step > 0) {
      if (tid == 0) {
        unsigned tgt = 16u*(unsigned)step;
        while (__hip_atomic_load(cnt, __ATOMIC_RELAXED, __HIP_MEMORY_SCOPE_AGENT) < tgt)
          __builtin_amdgcn_s_sleep(4);
      }
      __syncthreads();

      // ---- recurrent h_prev @ Whh^T (coherent loads, weights in regs) ----
      const u16* hrow[4];
#pragma unroll
      for (int mt = 0; mt < 4; ++mt)
        hrow[mt] = hbuf + ((size_t)((mt*16 + an)*512 + tprev) << 10) + dir*512;
#pragma unroll 4
      for (int kc = 0; kc < 16; ++kc) {
        v8s af[4];
#pragma unroll
        for (int mt = 0; mt < 4; ++mt) af[mt] = load_h16(hrow[mt] + kc*32 + ak);
#pragma unroll
        for (int nt = 0; nt < 2; ++nt)
#pragma unroll
          for (int mt = 0; mt < 4; ++mt)
            acc[mt][nt] = __builtin_amdgcn_mfma_f32_16x16x32_bf16(af[mt], whh_reg[nt][kc], acc[mt][nt], 0,0,0);
      }
    }

    // ---- exchange gates across waves ----
#pragma unroll
    for (int mt=0; mt<4; ++mt)
#pragma unroll
      for (int nt=0; nt<2; ++nt)
#pragma unroll
        for (int r4=0; r4<4; ++r4) {
          int n = mt*16 + ((lane>>4)<<2) + r4;
          int u = nt*16 + an;
          glds[w*2048 + n*32 + u] = acc[mt][nt][r4];
        }
    __syncthreads();

    // ---- pointwise cell update (c in registers) -> hlds ----
#pragma unroll
    for (int it = 0; it < 8; ++it) {
      int n = (tid >> 5) + it*8;
      float g0 = glds[0*2048 + n*32 + u_pw] + bsum[0];
      float g1 = glds[1*2048 + n*32 + u_pw] + bsum[1];
      float g2 = glds[2*2048 + n*32 + u_pw] + bsum[2];
      float g3 = glds[3*2048 + n*32 + u_pw] + bsum[3];
      float cn = sigm(g1)*creg[it] + sigm(g0)*ftanh(g2);
      creg[it] = cn;
      float h = sigm(g3)*ftanh(cn);
      hlds[n*32 + u_pw] = f2bf(h);
    }
    __syncthreads();

    // ---- packed write-through h store (16B per thread) ----
    {
      int n  = tid >> 2;
      int ub = (tid & 3) << 3;
      u64 a = *(const u64*)&hlds[n*32 + ub];
      u64 b = *(const u64*)&hlds[n*32 + ub + 4];
      store_h16(hbuf + ((size_t)(n*512 + t) << 10) + dir*512 + ug*32 + ub, a, b);
    }
    __syncthreads();   // drains vmcnt of all waves -> stores at coherence point

    if (tid == 0)
      __hip_atomic_fetch_add(cnt, 1u, __ATOMIC_RELAXED, __HIP_MEMORY_SCOPE_AGENT);
  }
}

// ---------------------------------------------------------------------------
// Fused attention step: per-batch block computes e -> masked softmax -> context
// ---------------------------------------------------------------------------
__global__ __launch_bounds__(256) void attn_step(
    const float* __restrict__ qbuf, const u16* __restrict__ Uah,
    const u16* __restrict__ hid, const int* __restrict__ seq_len,
    const u16* __restrict__ vaW, const u16* __restrict__ vab,
    u16* __restrict__ catb)
{
  int n = blockIdx.x, tid = threadIdx.x;
  __shared__ float qs[1024];
  __shared__ float vas[1024];
  __shared__ float es[512];
  __shared__ float red[8];
  for (int d=tid; d<1024; d+=256){ qs[d]=qbuf[n*1024+d]; vas[d]=bf2f(vaW[d]); }
  __syncthreads();
  int sl = seq_len[n];
  float vb = bf2f(vab[0]);
  for (int l=tid; l<512; l+=256) {
    const u16* up = Uah + ((size_t)n*512 + l)*1024;
    float a = 0.f;
    for (int d=0; d<1024; d+=8) {
      v8s uv = *(const v8s*)(up + d);
#pragma unroll
      for (int e=0;e<8;++e)
        a = fmaf(ftanh(bf2f((u16)uv[e]) + qs[d+e]), vas[d+e], a);
    }
    float ev = a + vb;
    if (l >= sl) ev += NEG_INF;
    es[l] = ev;
  }
  __syncthreads();
  float m = -3.4e38f;
  for (int l=tid; l<512; l+=256) m = fmaxf(m, es[l]);
#pragma unroll
  for (int off=1; off<64; off<<=1) m = fmaxf(m, __shfl_xor(m, off));
  if ((tid&63)==0) red[tid>>6] = m;
  __syncthreads();
  m = fmaxf(fmaxf(red[0],red[1]), fmaxf(red[2],red[3]));
  float s = 0.f;
  for (int l=tid; l<512; l+=256){ float p = __expf(es[l]-m); es[l]=p; s+=p; }
#pragma unroll
  for (int off=1; off<64; off<<=1) s += __shfl_xor(s, off);
  if ((tid&63)==0) red[4+(tid>>6)] = s;
  __syncthreads();
  float inv = 1.f/(red[4]+red[5]+red[6]+red[7]);
  int d0 = tid*4;
  float c0=0,c1=0,c2=0,c3=0;
  for (int l=0; l<512; ++l) {
    float a = es[l];
    const u16* hp = hid + ((size_t)n*512 + l)*1024 + d0;
    v4s hv = *(const v4s*)hp;
    c0 = fmaf(a, bf2f((u16)hv[0]), c0);
    c1 = fmaf(a, bf2f((u16)hv[1]), c1);
    c2 = fmaf(a, bf2f((u16)hv[2]), c2);
    c3 = fmaf(a, bf2f((u16)hv[3]), c3);
  }
  catb[n*2048 + d0 + 0] = f2bf(c0*inv);
  catb[n*2048 + d0 + 1] = f2bf(c1*inv);
  catb[n*2048 + d0 + 2] = f2bf(c2*inv);
  catb[n*2048 + d0 + 3] = f2bf(c3*inv);
}

// decoder pointwise: c = sig(i)*tanh(g); s = sig(o)*tanh(c)
__global__ void dec_pw(const float* __restrict__ g, u16* __restrict__ scat,
                       u16* __restrict__ catb, int it)
{
  int idx = blockIdx.x*256 + threadIdx.x;
  int n = idx >> 10, d = idx & 1023;
  float gi = g[(size_t)n*4096 + d];
  float gg = g[(size_t)n*4096 + 2048 + d];
  float go = g[(size_t)n*4096 + 3072 + d];
  float c = sigm(gi)*ftanh(gg);
  float s = sigm(go)*ftanh(c);
  u16 hb = f2bf(s);
  scat[((size_t)n*11 + it)*1024 + d] = hb;
  catb[n*2048 + 1024 + d] = hb;
}

__global__ void fill_sentinel(float* out, int nel){
  int i = blockIdx.x*256 + threadIdx.x;
  if (i < nel) out[i] = 12345.0f;
}

// ---------------------------------------------------------------------------
extern "C" void kernel_launch(void* const* d_in, const int* in_sizes, int n_in,
                              void* d_out, int out_size, void* d_ws, size_t ws_size,
                              hipStream_t stream)
{
  const int* X      = (const int*)d_in[0];
  const int* seqlen = (const int*)d_in[1];
  float* out = (float*)d_out;
  char* ws = (char*)d_ws;

  struct Seg { int idx; int n; };
  static const Seg segs[31] = {
    {2, 4096000},
    {3, 262144},{4,1048576},{5,2048},{6,2048},
    {7, 262144},{8,1048576},{9,2048},{10,2048},
    {11,2097152},{12,1048576},{13,2048},{14,2048},
    {15,2097152},{16,1048576},{17,2048},{18,2048},
    {19,1048576},{20,1024},
    {21,1048576},{22,1024},
    {23,1048576},{24,1024},
    {25,1024},{26,1},
    {27,4194304},{28,4194304},{29,4096},{30,4096},
    {31,10240000},{32,10000},
  };
  const u16* bp[33];
  CvtTab tab;
  size_t aoff = 0;
  for (int i = 0; i < 31; ++i) {
    bp[segs[i].idx] = (const u16*)(ws) + aoff;
    tab.src[i] = (const float*)d_in[segs[i].idx];
    tab.off[i] = (unsigned)aoff;
    tab.n[i]   = (unsigned)segs[i].n;
    aoff += (size_t)((segs[i].n + 7) & ~7);
  }
  tab.total = (unsigned)aoff;
  size_t arena_bytes = ((aoff*2 + 255) & ~(size_t)255);

  const size_t H0_OFF   = arena_bytes;
  const size_t HID_OFF  = H0_OFF   + 67108864;
  const size_t BAR_OFF  = HID_OFF  + 67108864;   // 1 KB of barrier counters
  const size_t CATB_OFF = BAR_OFF  + 1024;
  const size_t QBUF_OFF = CATB_OFF + 262144;
  const size_t GDEC_OFF = QBUF_OFF + 262144;
  const size_t SCAT_OFF = GDEC_OFF + 1048576;
  const size_t NEED     = SCAT_OFF + 1441792;

  if (ws_size < NEED) {
    fill_sentinel<<<(out_size+255)/256, 256, 0, stream>>>(out, out_size);
    return;
  }

  u16*      h0   = (u16*)(ws + H0_OFF);
  u16*      Uah  = (u16*)(ws + H0_OFF);   // alias: h0 dead after encoder
  u16*      hid  = (u16*)(ws + HID_OFF);
  unsigned* bar  = (unsigned*)(ws + BAR_OFF);
  u16*      catb = (u16*)(ws + CATB_OFF);
  float*    qbuf = (float*)(ws + QBUF_OFF);
  float*    gdec = (float*)(ws + GDEC_OFF);
  u16*      scat = (u16*)(ws + SCAT_OFF);

  hipMemsetAsync(ws + BAR_OFF, 0, 1024, stream);

  {
    unsigned nth = (unsigned)(aoff / 8);
    cvt_all<<<(nth + 255)/256, 256, 0, stream>>>(tab, (u16*)ws);
  }

  // ---- encoder layer 0 (persistent scan, Whh in registers) ----
  lstm_scan<0><<<32, 256, 0, stream>>>(
      bp[2], X, bp[3], bp[7], bp[4], bp[8],
      bp[5], bp[6], bp[9], bp[10], h0, bar);

  // ---- encoder layer 1 (persistent scan, on-the-fly x-projection) ----
  lstm_scan<1><<<32, 256, 0, stream>>>(
      h0, nullptr, bp[11], bp[15], bp[12], bp[16],
      bp[13], bp[14], bp[17], bp[18], hid, bar + 128);

  // ---- attention precompute ----
  gemm_bf16<<<dim3(256,8), 256, 0, stream>>>(hid, 1024, bp[23], bp[24], nullptr,
      Uah, 1024, 32768, 1024, 1024, GF_OUTBF16);
  gemm_bf16<<<dim3(1,8), 256, 0, stream>>>(hid, 524288, bp[19], bp[20], nullptr,
      catb + 1024, 2048, 64, 1024, 1024, GF_OUTBF16 | GF_TANH);

  // ---- 11 decoder steps ----
  for (int it = 0; it < 11; ++it) {
    gemm_bf16<<<dim3(1,8), 256, 0, stream>>>(catb + 1024, 2048, bp[21], bp[22], nullptr,
        qbuf, 1024, 64, 1024, 1024, 0);
    attn_step<<<64, 256, 0, stream>>>(qbuf, Uah, hid, seqlen, bp[25], bp[26], catb);
    gemm_bf16<<<dim3(1,32), 256, 0, stream>>>(catb, 2048, bp[27], bp[29], bp[30],
        gdec, 4096, 64, 4096, 1024, 0);
    gemm_bf16<<<dim3(1,32), 256, 0, stream>>>(catb + 1024, 2048, bp[28], nullptr, nullptr,
        gdec, 4096, 64, 4096, 1024, GF_ACCUM);
    dec_pw<<<256, 256, 0, stream>>>(gdec, scat, catb, it);
  }

  // ---- classifier (f32 output) ----
  gemm_bf16<<<dim3(6,79), 256, 0, stream>>>(scat, 1024, bp[31], bp[32], nullptr,
      out, 10000, 704, 10000, 1024, 0);
}

// Round 5
// 27849.274 us; speedup vs baseline: 1.3462x; 1.3462x over previous
//
#include <hip/hip_runtime.h>
#include <stdint.h>

#define NEG_INF -100000000.0f

typedef unsigned short u16;
typedef unsigned long long u64;
typedef __attribute__((ext_vector_type(8))) short v8s;
typedef __attribute__((ext_vector_type(4))) short v4s;
typedef __attribute__((ext_vector_type(4))) float v4f;

__device__ __forceinline__ float bf2f(u16 h){ return __uint_as_float(((unsigned)h)<<16); }
__device__ __forceinline__ u16 f2bf(float f){
  unsigned u = __float_as_uint(f);
  u = u + 0x7fffu + ((u>>16)&1u);
  return (u16)(u>>16);
}
__device__ __forceinline__ float sigm(float x){ return 1.0f/(1.0f+__expf(-x)); }
__device__ __forceinline__ float ftanh(float x){
  x = fminf(15.0f, fmaxf(-15.0f, x));
  float e = __expf(2.0f*x);
  return (e-1.0f)/(e+1.0f);
}

// write-through (coherence-point) 16B h store; loads of h are PLAIN (see scan notes)
__device__ __forceinline__ void store_h16(u16* p, u64 a, u64 b){
  __hip_atomic_store((u64*)p,     a, __ATOMIC_RELAXED, __HIP_MEMORY_SCOPE_AGENT);
  __hip_atomic_store((u64*)(p+4), b, __ATOMIC_RELAXED, __HIP_MEMORY_SCOPE_AGENT);
}

// ---------------------------------------------------------------------------
// Fused f32 -> bf16 arena conversion (all 31 float params in one launch)
// ---------------------------------------------------------------------------
struct CvtTab {
  const float* src[31];
  unsigned off[31];
  unsigned n[31];
  unsigned total;
};

__global__ __launch_bounds__(256) void cvt_all(CvtTab tab, u16* __restrict__ arena){
  unsigned e0 = (blockIdx.x*256u + threadIdx.x)*8u;
  if (e0 >= tab.total) return;
  int s = 0;
#pragma unroll 1
  for (int i = 1; i < 31; ++i) if (e0 >= tab.off[i]) s = i;
  unsigned rel = e0 - tab.off[s];
  const float* sp = tab.src[s] + rel;
  unsigned nn = tab.n[s];
  union { u16 h[8]; v8s v; } o;
  if (rel + 8 <= nn) {
    float4 a = *(const float4*)sp;
    float4 b = *(const float4*)(sp+4);
    o.h[0]=f2bf(a.x); o.h[1]=f2bf(a.y); o.h[2]=f2bf(a.z); o.h[3]=f2bf(a.w);
    o.h[4]=f2bf(b.x); o.h[5]=f2bf(b.y); o.h[6]=f2bf(b.z); o.h[7]=f2bf(b.w);
  } else {
#pragma unroll
    for (int k = 0; k < 8; ++k) o.h[k] = (rel + k < nn) ? f2bf(sp[k]) : (u16)0;
  }
  *(v8s*)(arena + e0) = o.v;
}

// ---------------------------------------------------------------------------
// Generic bf16 GEMM: C[M][N] = A[M][K] @ B[N][K]^T (+bias1+bias2)(+tanh)(+C)
// ---------------------------------------------------------------------------
#define GF_OUTBF16 1
#define GF_TANH    2
#define GF_ACCUM   4

__global__ __launch_bounds__(256) void gemm_bf16(
    const u16* __restrict__ A, long long lda,
    const u16* __restrict__ B,
    const u16* __restrict__ bias1, const u16* __restrict__ bias2,
    void* __restrict__ Cout, long long ldc,
    int M, int Nn, int K, int flags)
{
  __shared__ u16 As[8192];
  __shared__ u16 Bs[8192];
  int tid = threadIdx.x;
  int lane = tid & 63, w = tid >> 6;
  int wm = w >> 1, wn = w & 1;
  int bm = blockIdx.x * 128, bn = blockIdx.y * 128;

  v4f acc[4][4];
#pragma unroll
  for (int i=0;i<4;++i)
#pragma unroll
    for (int j=0;j<4;++j) acc[i][j] = (v4f){0.f,0.f,0.f,0.f};

#pragma unroll 1
  for (int ko = 0; ko < K; ko += 64) {
    __syncthreads();
#pragma unroll
    for (int it = 0; it < 8; ++it) {
      int c = tid + 256*it;
      int half = c >> 10;
      int cc = c & 1023;
      int r = cc >> 3;
      int kcb = cc & 7;
      const u16* src;
      if (half == 0) {
        int row = min(bm + r, M-1);
        src = A + (size_t)row*(size_t)lda + ko + (kcb<<3);
      } else {
        int row = min(bn + r, Nn-1);
        src = B + (size_t)row*(size_t)K + ko + (kcb<<3);
      }
      v8s v = *(const v8s*)src;
      char* base = (char*)(half ? Bs : As);
      *(v8s*)(base + (r<<7) + ((kcb<<4) ^ ((r&7)<<4))) = v;
    }
    __syncthreads();
#pragma unroll
    for (int ks = 0; ks < 2; ++ks) {
      v8s af[4], bfr[4];
#pragma unroll
      for (int mt=0; mt<4; ++mt) {
        int r = wm*64 + mt*16 + (lane & 15);
        int kb = (ks<<6) + ((lane>>4)<<4);
        af[mt] = *(const v8s*)((const char*)As + (r<<7) + (kb ^ ((r&7)<<4)));
      }
#pragma unroll
      for (int nt=0; nt<4; ++nt) {
        int r = wn*64 + nt*16 + (lane & 15);
        int kb = (ks<<6) + ((lane>>4)<<4);
        bfr[nt] = *(const v8s*)((const char*)Bs + (r<<7) + (kb ^ ((r&7)<<4)));
      }
#pragma unroll
      for (int mt=0; mt<4; ++mt)
#pragma unroll
        for (int nt=0; nt<4; ++nt)
          acc[mt][nt] = __builtin_amdgcn_mfma_f32_16x16x32_bf16(af[mt], bfr[nt], acc[mt][nt], 0,0,0);
    }
  }

#pragma unroll
  for (int mt=0; mt<4; ++mt) {
#pragma unroll
    for (int nt=0; nt<4; ++nt) {
      int col = bn + wn*64 + nt*16 + (lane&15);
      if (col >= Nn) continue;
      float b = 0.f;
      if (bias1) b += bf2f(bias1[col]);
      if (bias2) b += bf2f(bias2[col]);
#pragma unroll
      for (int r=0; r<4; ++r) {
        int row = bm + wm*64 + mt*16 + ((lane>>4)<<2) + r;
        if (row >= M) continue;
        float v = acc[mt][nt][r] + b;
        if (flags & GF_ACCUM) v += ((float*)Cout)[(size_t)row*(size_t)ldc + col];
        if (flags & GF_TANH) v = ftanh(v);
        if (flags & GF_OUTBF16) ((u16*)Cout)[(size_t)row*(size_t)ldc + col] = f2bf(v);
        else                    ((float*)Cout)[(size_t)row*(size_t)ldc + col] = v;
      }
    }
  }
}

// ---------------------------------------------------------------------------
// Persistent bidirectional LSTM scan.
// 32 blocks: dir = blk>>4, ug = blk&15 (32 units each). 4 waves = 4 gates.
// Coherence scheme (no fences, no atomic data loads):
//  - every hbuf 64B line is written exactly ONCE (one block, write-through
//    relaxed-atomic store) and read at most once per consumer block ->
//    consumer's plain cached load can never hit a stale L1/L2 line; it
//    misses to LLC where the write-through data lives.
//  - arrival counter: relaxed agent fetch_add after __syncthreads (vmcnt
//    drain); consumers poll relaxed then __syncthreads + compiler barrier.
// Whh slice (and L0 Wih) pinned in VGPRs via full unroll + asm "+v".
// ---------------------------------------------------------------------------
template<int LAYER>
__global__ __launch_bounds__(256, 1) void lstm_scan(
    const u16* __restrict__ xsrc,      // L0: embW ; L1: h0
    const int* __restrict__ Xidx,      // L0 only
    const u16* __restrict__ Wih_f, const u16* __restrict__ Wih_b,
    const u16* __restrict__ Whh_f, const u16* __restrict__ Whh_b,
    const u16* __restrict__ bih_f, const u16* __restrict__ bhh_f,
    const u16* __restrict__ bih_b, const u16* __restrict__ bhh_b,
    u16* __restrict__ hbuf,            // [64][512][1024], this layer's output
    unsigned* __restrict__ bar)
{
  constexpr int NCX = (LAYER==0) ? 4 : 32;   // x-projection K/32 chunks
  constexpr int KX  = NCX*32;
  __shared__ float glds[4*64*34];            // gate x (64 n, stride-34) -> 2-way max
  __shared__ u16   hlds[2048];

  const int tid = threadIdx.x, lane = tid & 63, w = tid >> 6;
  const int dir = blockIdx.x >> 4, ug = blockIdx.x & 15;
  const u16* Wih = dir ? Wih_b : Wih_f;
  const u16* Whh = dir ? Whh_b : Whh_f;
  unsigned* cnt = bar + dir*64;

  const int an = lane & 15;
  const int ak = (lane >> 4) << 3;

  const u16* wihp[2];
#pragma unroll
  for (int nt = 0; nt < 2; ++nt) {
    int j = w*512 + ug*32 + nt*16 + an;
    wihp[nt] = Wih + (size_t)j*KX;
  }

  // ---- Whh slice pinned in VGPRs (full unroll + asm pin) ----
  v8s whh_reg[2][16];
#pragma unroll
  for (int nt = 0; nt < 2; ++nt) {
    const u16* wp = Whh + (size_t)((w*512 + ug*32 + nt*16 + an))*512;
#pragma unroll
    for (int kc = 0; kc < 16; ++kc) {
      whh_reg[nt][kc] = *(const v8s*)(wp + kc*32 + ak);
      asm volatile("" : "+v"(whh_reg[nt][kc]));
    }
  }
  // ---- L0: Wih slice pinned too (K=128 -> 4 frags per nt) ----
  v8s wih0[2][(LAYER==0)?4:1];
  if constexpr (LAYER == 0) {
#pragma unroll
    for (int nt = 0; nt < 2; ++nt)
#pragma unroll
      for (int kc = 0; kc < 4; ++kc) {
        wih0[nt][kc] = *(const v8s*)(wihp[nt] + kc*32 + ak);
        asm volatile("" : "+v"(wih0[nt][kc]));
      }
  }

  const int u_pw = tid & 31, uj_pw = ug*32 + u_pw;
  float bsum[4];
  {
    const u16* bi = dir ? bih_b : bih_f;
    const u16* bh = dir ? bhh_b : bhh_f;
#pragma unroll
    for (int q = 0; q < 4; ++q)
      bsum[q] = bf2f(bi[q*512 + uj_pw]) + bf2f(bh[q*512 + uj_pw]);
  }
  float creg[8];
#pragma unroll
  for (int i = 0; i < 8; ++i) creg[i] = 0.f;

  for (int step = 0; step < 512; ++step) {
    const int t     = dir ? (511 - step) : step;
    const int tprev = dir ? (t + 1) : (t - 1);

    v4f acc[4][2];
#pragma unroll
    for (int i=0;i<4;++i){ acc[i][0]=(v4f){0,0,0,0}; acc[i][1]=(v4f){0,0,0,0}; }

    // ---- x-projection (independent of h_prev; overlaps barrier wait) ----
    {
      const u16* arow[4];
#pragma unroll
      for (int mt = 0; mt < 4; ++mt) {
        if constexpr (LAYER == 0) {
          int xr = Xidx[(mt*16 + an)*512 + t];
          arow[mt] = xsrc + (size_t)xr * 128;
        } else {
          arow[mt] = xsrc + ((size_t)((mt*16 + an)*512 + t) << 10);
        }
      }
#pragma unroll
      for (int kc = 0; kc < NCX; ++kc) {
        v8s af[4];
#pragma unroll
        for (int mt = 0; mt < 4; ++mt) af[mt] = *(const v8s*)(arow[mt] + kc*32 + ak);
#pragma unroll
        for (int nt = 0; nt < 2; ++nt) {
          v8s bfr;
          if constexpr (LAYER == 0) bfr = wih0[nt][kc];
          else                      bfr = *(const v8s*)(wihp[nt] + kc*32 + ak);
#pragma unroll
          for (int mt = 0; mt < 4; ++mt)
            acc[mt][nt] = __builtin_amdgcn_mfma_f32_16x16x32_bf16(af[mt], bfr, acc[mt][nt], 0,0,0);
        }
      }
    }

    // ---- wait for previous step's h ----
    if (step > 0) {
      if (tid == 0) {
        unsigned tgt = 16u*(unsigned)step;
        while (__hip_atomic_load(cnt, __ATOMIC_RELAXED, __HIP_MEMORY_SCOPE_AGENT) < tgt)
          __builtin_amdgcn_s_sleep(1);
      }
      __syncthreads();
      asm volatile("" ::: "memory");

      // ---- recurrent h_prev @ Whh^T : PLAIN pipelined loads, pinned weights ----
      const u16* hrow[4];
#pragma unroll
      for (int mt = 0; mt < 4; ++mt)
        hrow[mt] = hbuf + ((size_t)((mt*16 + an)*512 + tprev) << 10) + dir*512;
#pragma unroll
      for (int kc = 0; kc < 16; ++kc) {
        v8s af[4];
#pragma unroll
        for (int mt = 0; mt < 4; ++mt) af[mt] = *(const v8s*)(hrow[mt] + kc*32 + ak);
#pragma unroll
        for (int nt = 0; nt < 2; ++nt)
#pragma unroll
          for (int mt = 0; mt < 4; ++mt)
            acc[mt][nt] = __builtin_amdgcn_mfma_f32_16x16x32_bf16(af[mt], whh_reg[nt][kc], acc[mt][nt], 0,0,0);
      }
    }

    // ---- exchange gates across waves (stride-34 rows: <=2-way banks) ----
#pragma unroll
    for (int mt=0; mt<4; ++mt)
#pragma unroll
      for (int nt=0; nt<2; ++nt)
#pragma unroll
        for (int r4=0; r4<4; ++r4) {
          int n = mt*16 + ((lane>>4)<<2) + r4;
          int u = nt*16 + an;
          glds[w*2176 + n*34 + u] = acc[mt][nt][r4];
        }
    __syncthreads();

    // ---- pointwise cell update (c in registers) -> hlds ----
#pragma unroll
    for (int it = 0; it < 8; ++it) {
      int n = (tid >> 5) + it*8;
      float g0 = glds[0*2176 + n*34 + u_pw] + bsum[0];
      float g1 = glds[1*2176 + n*34 + u_pw] + bsum[1];
      float g2 = glds[2*2176 + n*34 + u_pw] + bsum[2];
      float g3 = glds[3*2176 + n*34 + u_pw] + bsum[3];
      float cn = sigm(g1)*creg[it] + sigm(g0)*ftanh(g2);
      creg[it] = cn;
      float h = sigm(g3)*ftanh(cn);
      hlds[n*32 + u_pw] = f2bf(h);
    }
    __syncthreads();

    // ---- packed write-through h store (16B per thread; 64B line per block) ----
    {
      int n  = tid >> 2;
      int ub = (tid & 3) << 3;
      u64 a = *(const u64*)&hlds[n*32 + ub];
      u64 b = *(const u64*)&hlds[n*32 + ub + 4];
      store_h16(hbuf + ((size_t)(n*512 + t) << 10) + dir*512 + ug*32 + ub, a, b);
    }
    asm volatile("" ::: "memory");
    __syncthreads();   // vmcnt drain -> stores at coherence point

    if (tid == 0)
      __hip_atomic_fetch_add(cnt, 1u, __ATOMIC_RELAXED, __HIP_MEMORY_SCOPE_AGENT);
  }
}

// ---------------------------------------------------------------------------
// Fused attention step: per-batch block computes e -> masked softmax -> context
// ---------------------------------------------------------------------------
__global__ __launch_bounds__(256) void attn_step(
    const float* __restrict__ qbuf, const u16* __restrict__ Uah,
    const u16* __restrict__ hid, const int* __restrict__ seq_len,
    const u16* __restrict__ vaW, const u16* __restrict__ vab,
    u16* __restrict__ catb)
{
  int n = blockIdx.x, tid = threadIdx.x;
  __shared__ float qs[1024];
  __shared__ float vas[1024];
  __shared__ float es[512];
  __shared__ float red[8];
  for (int d=tid; d<1024; d+=256){ qs[d]=qbuf[n*1024+d]; vas[d]=bf2f(vaW[d]); }
  __syncthreads();
  int sl = seq_len[n];
  float vb = bf2f(vab[0]);
  for (int l=tid; l<512; l+=256) {
    const u16* up = Uah + ((size_t)n*512 + l)*1024;
    float a = 0.f;
    for (int d=0; d<1024; d+=8) {
      v8s uv = *(const v8s*)(up + d);
#pragma unroll
      for (int e=0;e<8;++e)
        a = fmaf(ftanh(bf2f((u16)uv[e]) + qs[d+e]), vas[d+e], a);
    }
    float ev = a + vb;
    if (l >= sl) ev += NEG_INF;
    es[l] = ev;
  }
  __syncthreads();
  float m = -3.4e38f;
  for (int l=tid; l<512; l+=256) m = fmaxf(m, es[l]);
#pragma unroll
  for (int off=1; off<64; off<<=1) m = fmaxf(m, __shfl_xor(m, off));
  if ((tid&63)==0) red[tid>>6] = m;
  __syncthreads();
  m = fmaxf(fmaxf(red[0],red[1]), fmaxf(red[2],red[3]));
  float s = 0.f;
  for (int l=tid; l<512; l+=256){ float p = __expf(es[l]-m); es[l]=p; s+=p; }
#pragma unroll
  for (int off=1; off<64; off<<=1) s += __shfl_xor(s, off);
  if ((tid&63)==0) red[4+(tid>>6)] = s;
  __syncthreads();
  float inv = 1.f/(red[4]+red[5]+red[6]+red[7]);
  int d0 = tid*4;
  float c0=0,c1=0,c2=0,c3=0;
  for (int l=0; l<512; ++l) {
    float a = es[l];
    const u16* hp = hid + ((size_t)n*512 + l)*1024 + d0;
    v4s hv = *(const v4s*)hp;
    c0 = fmaf(a, bf2f((u16)hv[0]), c0);
    c1 = fmaf(a, bf2f((u16)hv[1]), c1);
    c2 = fmaf(a, bf2f((u16)hv[2]), c2);
    c3 = fmaf(a, bf2f((u16)hv[3]), c3);
  }
  catb[n*2048 + d0 + 0] = f2bf(c0*inv);
  catb[n*2048 + d0 + 1] = f2bf(c1*inv);
  catb[n*2048 + d0 + 2] = f2bf(c2*inv);
  catb[n*2048 + d0 + 3] = f2bf(c3*inv);
}

// decoder pointwise: c = sig(i)*tanh(g); s = sig(o)*tanh(c)
__global__ void dec_pw(const float* __restrict__ g, u16* __restrict__ scat,
                       u16* __restrict__ catb, int it)
{
  int idx = blockIdx.x*256 + threadIdx.x;
  int n = idx >> 10, d = idx & 1023;
  float gi = g[(size_t)n*4096 + d];
  float gg = g[(size_t)n*4096 + 2048 + d];
  float go = g[(size_t)n*4096 + 3072 + d];
  float c = sigm(gi)*ftanh(gg);
  float s = sigm(go)*ftanh(c);
  u16 hb = f2bf(s);
  scat[((size_t)n*11 + it)*1024 + d] = hb;
  catb[n*2048 + 1024 + d] = hb;
}

__global__ void fill_sentinel(float* out, int nel){
  int i = blockIdx.x*256 + threadIdx.x;
  if (i < nel) out[i] = 12345.0f;
}

// ---------------------------------------------------------------------------
extern "C" void kernel_launch(void* const* d_in, const int* in_sizes, int n_in,
                              void* d_out, int out_size, void* d_ws, size_t ws_size,
                              hipStream_t stream)
{
  const int* X      = (const int*)d_in[0];
  const int* seqlen = (const int*)d_in[1];
  float* out = (float*)d_out;
  char* ws = (char*)d_ws;

  struct Seg { int idx; int n; };
  static const Seg segs[31] = {
    {2, 4096000},
    {3, 262144},{4,1048576},{5,2048},{6,2048},
    {7, 262144},{8,1048576},{9,2048},{10,2048},
    {11,2097152},{12,1048576},{13,2048},{14,2048},
    {15,2097152},{16,1048576},{17,2048},{18,2048},
    {19,1048576},{20,1024},
    {21,1048576},{22,1024},
    {23,1048576},{24,1024},
    {25,1024},{26,1},
    {27,4194304},{28,4194304},{29,4096},{30,4096},
    {31,10240000},{32,10000},
  };
  const u16* bp[33];
  CvtTab tab;
  size_t aoff = 0;
  for (int i = 0; i < 31; ++i) {
    bp[segs[i].idx] = (const u16*)(ws) + aoff;
    tab.src[i] = (const float*)d_in[segs[i].idx];
    tab.off[i] = (unsigned)aoff;
    tab.n[i]   = (unsigned)segs[i].n;
    aoff += (size_t)((segs[i].n + 7) & ~7);
  }
  tab.total = (unsigned)aoff;
  size_t arena_bytes = ((aoff*2 + 255) & ~(size_t)255);

  const size_t H0_OFF   = arena_bytes;
  const size_t HID_OFF  = H0_OFF   + 67108864;
  const size_t BAR_OFF  = HID_OFF  + 67108864;
  const size_t CATB_OFF = BAR_OFF  + 1024;
  const size_t QBUF_OFF = CATB_OFF + 262144;
  const size_t GDEC_OFF = QBUF_OFF + 262144;
  const size_t SCAT_OFF = GDEC_OFF + 1048576;
  const size_t NEED     = SCAT_OFF + 1441792;

  if (ws_size < NEED) {
    fill_sentinel<<<(out_size+255)/256, 256, 0, stream>>>(out, out_size);
    return;
  }

  u16*      h0   = (u16*)(ws + H0_OFF);
  u16*      Uah  = (u16*)(ws + H0_OFF);   // alias: h0 dead after encoder
  u16*      hid  = (u16*)(ws + HID_OFF);
  unsigned* bar  = (unsigned*)(ws + BAR_OFF);
  u16*      catb = (u16*)(ws + CATB_OFF);
  float*    qbuf = (float*)(ws + QBUF_OFF);
  float*    gdec = (float*)(ws + GDEC_OFF);
  u16*      scat = (u16*)(ws + SCAT_OFF);

  hipMemsetAsync(ws + BAR_OFF, 0, 1024, stream);

  {
    unsigned nth = (unsigned)(aoff / 8);
    cvt_all<<<(nth + 255)/256, 256, 0, stream>>>(tab, (u16*)ws);
  }

  // ---- encoder layer 0 (persistent scan) ----
  lstm_scan<0><<<32, 256, 0, stream>>>(
      bp[2], X, bp[3], bp[7], bp[4], bp[8],
      bp[5], bp[6], bp[9], bp[10], h0, bar);

  // ---- encoder layer 1 (persistent scan, on-the-fly x-projection) ----
  lstm_scan<1><<<32, 256, 0, stream>>>(
      h0, nullptr, bp[11], bp[15], bp[12], bp[16],
      bp[13], bp[14], bp[17], bp[18], hid, bar + 128);

  // ---- attention precompute ----
  gemm_bf16<<<dim3(256,8), 256, 0, stream>>>(hid, 1024, bp[23], bp[24], nullptr,
      Uah, 1024, 32768, 1024, 1024, GF_OUTBF16);
  gemm_bf16<<<dim3(1,8), 256, 0, stream>>>(hid, 524288, bp[19], bp[20], nullptr,
      catb + 1024, 2048, 64, 1024, 1024, GF_OUTBF16 | GF_TANH);

  // ---- 11 decoder steps ----
  for (int it = 0; it < 11; ++it) {
    gemm_bf16<<<dim3(1,8), 256, 0, stream>>>(catb + 1024, 2048, bp[21], bp[22], nullptr,
        qbuf, 1024, 64, 1024, 1024, 0);
    attn_step<<<64, 256, 0, stream>>>(qbuf, Uah, hid, seqlen, bp[25], bp[26], catb);
    gemm_bf16<<<dim3(1,32), 256, 0, stream>>>(catb, 2048, bp[27], bp[29], bp[30],
        gdec, 4096, 64, 4096, 1024, 0);
    gemm_bf16<<<dim3(1,32), 256, 0, stream>>>(catb + 1024, 2048, bp[28], nullptr, nullptr,
        gdec, 4096, 64, 4096, 1024, GF_ACCUM);
    dec_pw<<<256, 256, 0, stream>>>(gdec, scat, catb, it);
  }

  // ---- classifier (f32 output) ----
  gemm_bf16<<<dim3(6,79), 256, 0, stream>>>(scat, 1024, bp[31], bp[32], nullptr,
      out, 10000, 704, 10000, 1024, 0);
}